// Round 2
// baseline (314.950 us; speedup 1.0000x reference)
//
#include <hip/hip_runtime.h>

__device__ __forceinline__ float fast_rcp(float x) {
    return __builtin_amdgcn_rcpf(x);
}

__device__ __forceinline__ float tanh_fast(float x) {
    // tanh(x) = 1 - 2/(exp(2x)+1);  exp(2x) = exp2(2*log2(e)*x)
    float e = exp2f(x * 2.8853900817779268f);
    return 1.0f - 2.0f * fast_rcp(e + 1.0f);
}

__global__ __launch_bounds__(256) void riemann_kernel(
    const float* __restrict__ P, const float* __restrict__ U,
    const float* __restrict__ F, const float* __restrict__ cmax,
    const float* __restrict__ cmin,
    const float* __restrict__ W1_ds, const float* __restrict__ b1_ds,
    const float* __restrict__ W2_ds, const float* __restrict__ b2_ds,
    const float* __restrict__ W1_dr, const float* __restrict__ b1_dr,
    const float* __restrict__ W2_dr, const float* __restrict__ b2_dr,
    const float* __restrict__ W1_rs, const float* __restrict__ b1_rs,
    const float* __restrict__ W2_rs, const float* __restrict__ b2_rs,
    float* __restrict__ out, int N) {
    int i = blockIdx.x * blockDim.x + threadIdx.x;
    if (i >= N) return;

    // ---- load P,U,F (3x2 row-major per cell = 6 consecutive floats) ----
    const float2* P2 = (const float2*)P + (size_t)i * 3;
    const float2* U2 = (const float2*)U + (size_t)i * 3;
    const float2* F2 = (const float2*)F + (size_t)i * 3;
    float2 Pa = P2[0], Pb = P2[1], Pc = P2[2];
    float2 Ua = U2[0], Ub = U2[1], Uc = U2[2];
    float2 Fa = F2[0], Fb = F2[1], Fc = F2[2];
    float cm = cmax[i];
    float cn = cmin[i];

    // ---- flip: P[1][1] > P[1][0] (sgn = {1,1,-1}; F uses -sgn) ----
    bool flip = Pb.y > Pb.x;
    float pf0 = flip ?  Pa.y :  Pa.x;   // rho L
    float pf1 = flip ?  Pa.x :  Pa.y;   // rho R
    float pf2 = flip ?  Pb.y :  Pb.x;   // p   L
    float pf3 = flip ?  Pb.x :  Pb.y;   // p   R
    float pf4 = flip ? -Pc.y :  Pc.x;   // v   L
    float pf5 = flip ? -Pc.x :  Pc.y;   // v   R

    float uf0 = flip ?  Ua.y :  Ua.x;
    float uf1 = flip ?  Ua.x :  Ua.y;
    float uf2 = flip ?  Ub.y :  Ub.x;
    float uf3 = flip ?  Ub.x :  Ub.y;
    float uf4 = flip ? -Uc.y :  Uc.x;
    float uf5 = flip ? -Uc.x :  Uc.y;

    float ff0 = flip ? -Fa.y :  Fa.x;
    float ff1 = flip ? -Fa.x :  Fa.y;
    float ff2 = flip ? -Fb.y :  Fb.x;
    float ff3 = flip ? -Fb.x :  Fb.y;
    float ff4 = flip ?  Fc.y :  Fc.x;
    float ff5 = flip ?  Fc.x :  Fc.y;

    // ---- discrete decisions in f64 to match the np-f64 reference ----
    // (f32 knife-edges on label/cont/vac flip ~1 cell per 1e6 -> absmax ~0.4)
    double rho0 = (double)pf0, rho1 = (double)pf1;
    double p0   = (double)pf2, p1   = (double)pf3;
    double v0   = (double)pf4, v1   = (double)pf5;
    const double g = 5.0 / 3.0;

    // cont: f64 subtraction of f32 values is exact
    double dd0 = fabs(rho1 - rho0);
    double dd1 = fabs(p1 - p0);
    double dd2 = fabs(v1 - v0);
    bool cont = fmax(fmax(dd0, dd1), dd2) < 0.005;

    double c0 = sqrt(g * p0 / rho0);
    double c1 = sqrt(g * p1 / rho1);
    double dv = v1 - v0;
    double z = (g - 1.0) / (2.0 * g);
    double num = c0 + c1 - 0.5 * (g - 1.0) * dv;
    double den = c0 / pow(p0, z) + c1 / pow(p1, z);
    double ps = pow(fmax(num / den, 1e-8), 1.0 / z);
    bool vac = dv >= 2.0 / (g - 1.0) * (c0 + c1);
    bool drb = ps < fmin(p0, p1);
    bool dsb = ps > fmax(p0, p1);
    int label = vac ? 3 : (drb ? 1 : (dsb ? 0 : 2));

    // ---- HLLE flux (f32, continuous -> threshold-safe) ----
    float inv = 1.0f / (cm - cn);
    float cmn = cm * cn;
    float h0 = (cm * ff0 - cn * ff1 + cmn * (uf1 - uf0)) * inv;
    float h1 = (cm * ff2 - cn * ff3 + cmn * (uf3 - uf2)) * inv;
    float h2 = (cm * ff4 - cn * ff5 + cmn * (uf5 - uf4)) * inv;

    // ---- features (Pf,Uf,Ff row-major, cmax, cmin) ----
    float feats[20] = {pf0, pf1, pf2, pf3, pf4, pf5,
                       uf0, uf1, uf2, uf3, uf4, uf5,
                       ff0, ff1, ff2, ff3, ff4, ff5,
                       cm,  cn};

    // ---- three MLPs; weights wave-uniform -> scalar loads; select by label ----
    float o0 = 0.0f, o1 = 0.0f, o2 = 0.0f;
#pragma unroll 1
    for (int m = 0; m < 3; ++m) {
        const float* W1 = (m == 0) ? W1_ds : ((m == 1) ? W1_dr : W1_rs);
        const float* b1 = (m == 0) ? b1_ds : ((m == 1) ? b1_dr : b1_rs);
        const float* W2 = (m == 0) ? W2_ds : ((m == 1) ? W2_dr : W2_rs);
        const float* b2 = (m == 0) ? b2_ds : ((m == 1) ? b2_dr : b2_rs);

        float a0 = b2[0], a1 = b2[1], a2 = b2[2];
#pragma unroll 4
        for (int j = 0; j < 64; ++j) {
            float h = b1[j];
#pragma unroll
            for (int k = 0; k < 20; ++k) {
                h = fmaf(feats[k], W1[k * 64 + j], h);
            }
            float t = tanh_fast(h);
            a0 = fmaf(t, W2[j * 3 + 0], a0);
            a1 = fmaf(t, W2[j * 3 + 1], a1);
            a2 = fmaf(t, W2[j * 3 + 2], a2);
        }
        if (label == m) { o0 = a0; o1 = a1; o2 = a2; }
    }

    // ---- contact override, then un-flip (flux * -sgn = {-,-,+}) ----
    if (cont) { o0 = h0; o1 = h1; o2 = h2; }
    if (flip) { o0 = -o0; o1 = -o1; }

    out[(size_t)i * 3 + 0] = o0;
    out[(size_t)i * 3 + 1] = o1;
    out[(size_t)i * 3 + 2] = o2;
}

extern "C" void kernel_launch(void* const* d_in, const int* in_sizes, int n_in,
                              void* d_out, int out_size, void* d_ws, size_t ws_size,
                              hipStream_t stream) {
    const float* P     = (const float*)d_in[0];
    const float* U     = (const float*)d_in[1];
    const float* F     = (const float*)d_in[2];
    const float* cmax  = (const float*)d_in[3];
    const float* cmin  = (const float*)d_in[4];
    const float* W1_ds = (const float*)d_in[5];
    const float* b1_ds = (const float*)d_in[6];
    const float* W2_ds = (const float*)d_in[7];
    const float* b2_ds = (const float*)d_in[8];
    const float* W1_dr = (const float*)d_in[9];
    const float* b1_dr = (const float*)d_in[10];
    const float* W2_dr = (const float*)d_in[11];
    const float* b2_dr = (const float*)d_in[12];
    const float* W1_rs = (const float*)d_in[13];
    const float* b1_rs = (const float*)d_in[14];
    const float* W2_rs = (const float*)d_in[15];
    const float* b2_rs = (const float*)d_in[16];

    int N = in_sizes[3];  // cmax has N elements
    float* out = (float*)d_out;

    dim3 block(256);
    dim3 grid((N + 255) / 256);
    hipLaunchKernelGGL(riemann_kernel, grid, block, 0, stream,
                       P, U, F, cmax, cmin,
                       W1_ds, b1_ds, W2_ds, b2_ds,
                       W1_dr, b1_dr, W2_dr, b2_dr,
                       W1_rs, b1_rs, W2_rs, b2_rs,
                       out, N);
}